// Round 1
// 1029.400 us; speedup vs baseline: 1.1275x; 1.1275x over previous
//
#include <hip/hip_runtime.h>
#include <math.h>

#define B_ 16
#define T_ 4
#define D_ 1024
#define H_ 16
#define DH_ 64
#define S_ 8192
#define NW 8                        // waves per attention block
#define SPLIT 4                     // S-chunks per (b,h)
#define SCH (S_ / SPLIT)            // 2048 rows per block
#define ROWS_PER_WAVE (SCH / NW)    // 256
#define UNROLL 4
#define PSTR 68                     // partial stride: o[64], m, l, pad

// Single-instruction 2^x (inputs are <= 0; v_exp_f32 handles -huge -> 0).
__device__ __forceinline__ float exp2_(float x) {
  float r;
  asm("v_exp_f32 %0, %1" : "=v"(r) : "v"(x));
  return r;
}

// ---------------------------------------------------------------------------
// Batched online-softmax step: UNROLL=4 consecutive rows of this lane's
// stream, ONE max/rescale per t instead of one per row. All score math is in
// log2 domain (q pre-scaled by 0.125*log2(e)), so exp == v_exp_f32.
// Lane layout: lane = s_sub*16 + d4; kf/vf hold dims d4*4..d4*4+3.
// ---------------------------------------------------------------------------
__device__ __forceinline__ void online_step4(const float4* q4, const float4* kf,
                                             const float4* vf, float* m, float* l,
                                             float4* o) {
  float sc[UNROLL][T_];
#pragma unroll
  for (int u = 0; u < UNROLL; ++u)
#pragma unroll
    for (int t = 0; t < T_; ++t)
      sc[u][t] = q4[t].x * kf[u].x + q4[t].y * kf[u].y + q4[t].z * kf[u].z +
                 q4[t].w * kf[u].w;
#pragma unroll
  for (int mask = 1; mask < 16; mask <<= 1)
#pragma unroll
    for (int u = 0; u < UNROLL; ++u)
#pragma unroll
      for (int t = 0; t < T_; ++t) sc[u][t] += __shfl_xor(sc[u][t], mask);
#pragma unroll
  for (int t = 0; t < T_; ++t) {
    float nm = fmaxf(fmaxf(sc[0][t], sc[1][t]), fmaxf(sc[2][t], sc[3][t]));
    nm = fmaxf(nm, m[t]);
    float al = exp2_(m[t] - nm);
    float p0 = exp2_(sc[0][t] - nm);
    float p1 = exp2_(sc[1][t] - nm);
    float p2 = exp2_(sc[2][t] - nm);
    float p3 = exp2_(sc[3][t] - nm);
    m[t] = nm;
    l[t] = fmaf(l[t], al, (p0 + p1) + (p2 + p3));
    float ax = p0 * vf[0].x; ax = fmaf(p1, vf[1].x, ax); ax = fmaf(p2, vf[2].x, ax); ax = fmaf(p3, vf[3].x, ax);
    float ay = p0 * vf[0].y; ay = fmaf(p1, vf[1].y, ay); ay = fmaf(p2, vf[2].y, ay); ay = fmaf(p3, vf[3].y, ay);
    float az = p0 * vf[0].z; az = fmaf(p1, vf[1].z, az); az = fmaf(p2, vf[2].z, az); az = fmaf(p3, vf[3].z, az);
    float aw = p0 * vf[0].w; aw = fmaf(p1, vf[1].w, aw); aw = fmaf(p2, vf[2].w, aw); aw = fmaf(p3, vf[3].w, aw);
    o[t].x = fmaf(o[t].x, al, ax);
    o[t].y = fmaf(o[t].y, al, ay);
    o[t].z = fmaf(o[t].z, al, az);
    o[t].w = fmaf(o[t].w, al, aw);
  }
}

// Single-row step (the T_ freshly-projected K/V rows).
__device__ __forceinline__ void online_step1(const float4* q4, const float4& kf,
                                             const float4& vf, float* m, float* l,
                                             float4* o) {
  float sc[T_];
#pragma unroll
  for (int t = 0; t < T_; ++t)
    sc[t] = q4[t].x * kf.x + q4[t].y * kf.y + q4[t].z * kf.z + q4[t].w * kf.w;
#pragma unroll
  for (int mask = 1; mask < 16; mask <<= 1)
#pragma unroll
    for (int t = 0; t < T_; ++t) sc[t] += __shfl_xor(sc[t], mask);
#pragma unroll
  for (int t = 0; t < T_; ++t) {
    float nm = fmaxf(m[t], sc[t]);
    float al = exp2_(m[t] - nm);
    float p = exp2_(sc[t] - nm);
    m[t] = nm;
    l[t] = fmaf(l[t], al, p);
    o[t].x = fmaf(o[t].x, al, p * vf.x);
    o[t].y = fmaf(o[t].y, al, p * vf.y);
    o[t].z = fmaf(o[t].z, al, p * vf.z);
    o[t].w = fmaf(o[t].w, al, p * vf.w);
  }
}

// Merge two online-softmax streams held by lanes differing in bit `mask`.
__device__ __forceinline__ void merge_xor(int mask, float* m, float* l, float4* o) {
#pragma unroll
  for (int t = 0; t < T_; ++t) {
    float om = __shfl_xor(m[t], mask);
    float ol = __shfl_xor(l[t], mask);
    float4 oo;
    oo.x = __shfl_xor(o[t].x, mask);
    oo.y = __shfl_xor(o[t].y, mask);
    oo.z = __shfl_xor(o[t].z, mask);
    oo.w = __shfl_xor(o[t].w, mask);
    float nm = fmaxf(m[t], om);
    float ea = exp2_(m[t] - nm);
    float eb = exp2_(om - nm);
    m[t] = nm;
    l[t] = l[t] * ea + ol * eb;
    o[t].x = o[t].x * ea + oo.x * eb;
    o[t].y = o[t].y * ea + oo.y * eb;
    o[t].z = o[t].z * ea + oo.z * eb;
    o[t].w = o[t].w * ea + oo.w * eb;
  }
}

// ---------------------------------------------------------------------------
// Attention partial pass: one block per (b,h,split); 8 waves stream disjoint
// s-ranges of a 2048-row chunk, merge within the block, and write an
// unnormalized partial {o[64], m, l} per (block, t) to ws.
// Grid = B*H*SPLIT = 1024 blocks (4 blocks/CU target via launch_bounds).
// ---------------------------------------------------------------------------
__global__ __launch_bounds__(NW * 64, 4) void attn_kernel(
    const float* __restrict__ qkv, const float* __restrict__ cache_k,
    const float* __restrict__ cache_v, float* __restrict__ part) {
  const int blk = blockIdx.x;       // bh*SPLIT + split
  const int bh = blk >> 2;          // SPLIT == 4
  const int split = blk & 3;
  const int b = bh >> 4;
  const int h = bh & 15;
  const int tid = threadIdx.x;
  const int wave = tid >> 6;
  const int lane = tid & 63;
  const int s_sub = lane >> 4;
  const int d4 = lane & 15;

  // q fragments, pre-scaled by 1/sqrt(64) * log2(e) so scores live in log2.
  const float qs = 0.125f * 1.44269504088896340736f;
  float4 q4[T_];
#pragma unroll
  for (int t = 0; t < T_; ++t) {
    float4 q = *(const float4*)(qkv + (size_t)((b * T_ + t) * 3 * D_ + h * DH_ + d4 * 4));
    q4[t] = make_float4(q.x * qs, q.y * qs, q.z * qs, q.w * qs);
  }

  const float* kbase = cache_k + (size_t)b * S_ * D_ + h * DH_ + d4 * 4;
  const float* vbase = cache_v + (size_t)b * S_ * D_ + h * DH_ + d4 * 4;

  float m[T_], l[T_];
  float4 o[T_];
#pragma unroll
  for (int t = 0; t < T_; ++t) {
    m[t] = -1e30f;
    l[t] = 0.f;
    o[t] = make_float4(0.f, 0.f, 0.f, 0.f);
  }

  const int row0 = split * SCH + wave * ROWS_PER_WAVE + s_sub;
  for (int it = 0; it < ROWS_PER_WAVE / (4 * UNROLL); ++it) {
    const float* kp = kbase + (size_t)(row0 + it * 4 * UNROLL) * D_;
    const float* vp = vbase + (size_t)(row0 + it * 4 * UNROLL) * D_;
    float4 kf[UNROLL], vf[UNROLL];
#pragma unroll
    for (int u = 0; u < UNROLL; ++u) {  // all loads issued up front (MLP)
      kf[u] = *(const float4*)(kp + (size_t)u * 4 * D_);
      vf[u] = *(const float4*)(vp + (size_t)u * 4 * D_);
    }
    online_step4(q4, kf, vf, m, l, o);
  }

  // The T_ new K/V rows (s = S..S+3): handled once, by wave 0 of split 3.
  if (split == SPLIT - 1 && wave == 0) {
    const float* krow = qkv + (size_t)((b * T_ + s_sub) * 3 * D_ + D_ + h * DH_ + d4 * 4);
    const float* vrow = qkv + (size_t)((b * T_ + s_sub) * 3 * D_ + 2 * D_ + h * DH_ + d4 * 4);
    float4 kf = *(const float4*)krow;
    float4 vf = *(const float4*)vrow;
    online_step1(q4, kf, vf, m, l, o);
  }

  // Merge the 4 s_sub streams within the wave.
  merge_xor(16, m, l, o);
  merge_xor(32, m, l, o);

  // Cross-wave merge via LDS, then write the block's partial.
  __shared__ float lm[NW][T_];
  __shared__ float ll[NW][T_];
  __shared__ float lo[NW][T_][DH_];
  if (lane < 16) {
#pragma unroll
    for (int t = 0; t < T_; ++t) {
      if (lane == 0) {
        lm[wave][t] = m[t];
        ll[wave][t] = l[t];
      }
      *(float4*)(&lo[wave][t][lane * 4]) = o[t];
    }
  }
  __syncthreads();
  if (tid < DH_) {
#pragma unroll
    for (int t = 0; t < T_; ++t) {
      float M = lm[0][t];
#pragma unroll
      for (int w = 1; w < NW; ++w) M = fmaxf(M, lm[w][t]);
      float L = 0.f, O = 0.f;
#pragma unroll
      for (int w = 0; w < NW; ++w) {
        float e = exp2_(lm[w][t] - M);
        L = fmaf(ll[w][t], e, L);
        O = fmaf(lo[w][t][tid], e, O);
      }
      float* pp = part + ((size_t)blk * T_ + t) * PSTR;
      pp[tid] = O;
      if (tid == 0) {
        pp[DH_] = M;
        pp[DH_ + 1] = L;
      }
    }
  }
}

// ---------------------------------------------------------------------------
// Merge SPLIT partials per (b,h), normalize, write attn. Also zero-fills the
// final output buffer so the split-K GEMM2 can accumulate atomically.
// ---------------------------------------------------------------------------
__global__ __launch_bounds__(64) void attn_reduce(const float* __restrict__ part,
                                                  float* __restrict__ attn_out,
                                                  float4* __restrict__ out_zero) {
  const int bh = blockIdx.x;
  const int b = bh >> 4;
  const int h = bh & 15;
  const int d = threadIdx.x;
  out_zero[(size_t)bh * DH_ + d] = make_float4(0.f, 0.f, 0.f, 0.f);
#pragma unroll
  for (int t = 0; t < T_; ++t) {
    const float* p0 = part + ((size_t)(bh * SPLIT) * T_ + t) * PSTR;
    float M = p0[DH_];
#pragma unroll
    for (int sp = 1; sp < SPLIT; ++sp)
      M = fmaxf(M, p0[(size_t)sp * T_ * PSTR + DH_]);
    float L = 0.f, O = 0.f;
#pragma unroll
    for (int sp = 0; sp < SPLIT; ++sp) {
      const float* pp = p0 + (size_t)sp * T_ * PSTR;
      float e = exp2_(pp[DH_] - M);
      L = fmaf(pp[DH_ + 1], e, L);
      O = fmaf(pp[d], e, O);
    }
    attn_out[(size_t)(b * T_ + t) * D_ + h * DH_ + d] = O / L;
  }
}

// Zero-fill (for the split-K GEMM1 accumulator). One float4 per thread.
__global__ __launch_bounds__(256) void zero4(float4* __restrict__ p) {
  p[(size_t)blockIdx.x * 256 + threadIdx.x] = make_float4(0.f, 0.f, 0.f, 0.f);
}

// ---------------------------------------------------------------------------
// C[M=64, N] += A[64, K=1024] * W[N, K]^T over K-chunk [kb, kb+KCH).
// 64x64 output tile per block, 4x4 per thread, split-K over blockIdx.y with
// atomic accumulation. LDS padded to 68 so fragments read as float4
// (row stride 272 B = 16B-aligned; A-frag reads broadcast, B-frag 2-way).
// ---------------------------------------------------------------------------
__global__ __launch_bounds__(256) void gemm_xwt(const float* __restrict__ A,
                                                const float* __restrict__ W,
                                                float* __restrict__ C, int N,
                                                int KCH) {
  const int K = 1024;
  __shared__ float As[32][68];
  __shared__ float Bs[32][68];
  const int tid = threadIdx.x;
  const int n0 = blockIdx.x * 64;
  const int kb = blockIdx.y * KCH;
  const int tx = tid & 15;
  const int ty = tid >> 4;
  const int lrow = tid >> 2;     // 0..63
  const int lk = (tid & 3) * 8;  // 0,8,16,24

  float acc[4][4] = {};
  for (int k0 = kb; k0 < kb + KCH; k0 += 32) {
    float4 a0 = *(const float4*)(A + (size_t)lrow * K + k0 + lk);
    float4 a1 = *(const float4*)(A + (size_t)lrow * K + k0 + lk + 4);
    float4 b0 = *(const float4*)(W + (size_t)(n0 + lrow) * K + k0 + lk);
    float4 b1 = *(const float4*)(W + (size_t)(n0 + lrow) * K + k0 + lk + 4);
    As[lk + 0][lrow] = a0.x; As[lk + 1][lrow] = a0.y;
    As[lk + 2][lrow] = a0.z; As[lk + 3][lrow] = a0.w;
    As[lk + 4][lrow] = a1.x; As[lk + 5][lrow] = a1.y;
    As[lk + 6][lrow] = a1.z; As[lk + 7][lrow] = a1.w;
    Bs[lk + 0][lrow] = b0.x; Bs[lk + 1][lrow] = b0.y;
    Bs[lk + 2][lrow] = b0.z; Bs[lk + 3][lrow] = b0.w;
    Bs[lk + 4][lrow] = b1.x; Bs[lk + 5][lrow] = b1.y;
    Bs[lk + 6][lrow] = b1.z; Bs[lk + 7][lrow] = b1.w;
    __syncthreads();
#pragma unroll
    for (int kk = 0; kk < 32; ++kk) {
      const float4 av = *(const float4*)&As[kk][ty * 4];
      const float4 bv = *(const float4*)&Bs[kk][tx * 4];
      const float a[4] = {av.x, av.y, av.z, av.w};
      const float bb[4] = {bv.x, bv.y, bv.z, bv.w};
#pragma unroll
      for (int i = 0; i < 4; ++i)
#pragma unroll
        for (int j = 0; j < 4; ++j) acc[i][j] = fmaf(a[i], bb[j], acc[i][j]);
    }
    __syncthreads();
  }
#pragma unroll
  for (int i = 0; i < 4; ++i)
#pragma unroll
    for (int j = 0; j < 4; ++j)
      unsafeAtomicAdd(&C[(size_t)(ty * 4 + i) * N + n0 + tx * 4 + j], acc[i][j]);
}

extern "C" void kernel_launch(void* const* d_in, const int* in_sizes, int n_in,
                              void* d_out, int out_size, void* d_ws, size_t ws_size,
                              hipStream_t stream) {
  const float* x = (const float*)d_in[0];        // [B,T,D]
  const float* cache_k = (const float*)d_in[1];  // [B,S,H,DH]
  const float* cache_v = (const float*)d_in[2];  // [B,S,H,DH]
  const float* w_qkv = (const float*)d_in[3];    // [3D, D]
  const float* w_proj = (const float*)d_in[4];   // [D, D]
  float* out = (float*)d_out;                    // [B,T,D]

  float* qkv = (float*)d_ws;                            // 196608 floats
  float* attn = qkv + (size_t)B_ * T_ * 3 * D_;         // 65536 floats
  float* part = attn + (size_t)B_ * T_ * D_;            // 1024*4*68 floats

  // 0) zero the split-K accumulator for qkv (196608 floats = 49152 float4)
  zero4<<<192, 256, 0, stream>>>((float4*)qkv);
  // 1) qkv += x @ w_qkv^T   (M=64, N=3072, K split 8x128 -> 384 blocks)
  gemm_xwt<<<dim3(3 * D_ / 64, 8), 256, 0, stream>>>(x, w_qkv, qkv, 3 * D_, 128);
  // 2) attention partials over S-chunks (1024 blocks)
  attn_kernel<<<B_ * H_ * SPLIT, NW * 64, 0, stream>>>(qkv, cache_k, cache_v, part);
  // 3) merge partials -> attn; also zero `out` for gemm2's atomics
  attn_reduce<<<B_ * H_, 64, 0, stream>>>(part, attn, (float4*)out);
  // 4) out += attn @ w_proj^T   (M=64, N=1024, K split 8x128 -> 128 blocks)
  gemm_xwt<<<dim3(D_ / 64, 8), 256, 0, stream>>>(attn, w_proj, out, D_, 128);
}